// Round 10
// baseline (71.099 us; speedup 1.0000x reference)
//
#include <hip/hip_runtime.h>
#include <math.h>

#define B_   2
#define C_   256
#define H_   200
#define W_   272
#define HW_  (H_*W_)
#define NBIN 49
#define SCALE 0.0625f

typedef float v4f __attribute__((ext_vector_type(4)));

// ---------------------------------------------------------------------------
// bf16 helpers (staging only; all arithmetic stays f32)
// ---------------------------------------------------------------------------
__device__ __forceinline__ unsigned short f2bf(float f) {
    union { float f; unsigned int i; } v; v.f = f;
    unsigned int x = v.i;
    return (unsigned short)((x + 0x7FFFu + ((x >> 16) & 1u)) >> 16);   // RNE
}
__device__ __forceinline__ float bf2f(unsigned int u16) {
    union { unsigned int i; float f; } v; v.i = u16 << 16; return v.f;
}

// ---------------------------------------------------------------------------
// Geometry: bit-exact vs numpy f32 reference (verified: absmax 0.0 in R1).
// DO NOT TOUCH: fp contract off, same association order, f64 trig.
// ---------------------------------------------------------------------------
__device__ __forceinline__ float edge_mask(float yy, float xx) {
    return (yy > -1.0f && yy < (float)H_ && xx > -1.0f && xx < (float)W_) ? 1.0f : 0.0f;
}

__device__ void compute_geom(const float* __restrict__ rois, int r, int bin,
                             int& b, int& yt, int& yb, int& xl, int& xr,
                             float w[4]) {
#pragma clang fp contract(off)
    const float* rp = rois + r * 6;
    b = (int)rp[0];
    float cx = rp[1] * SCALE;
    float cy = rp[2] * SCALE;
    float rw = rp[3] * SCALE;
    float rh = rp[4] * SCALE;
    float theta = rp[5] * (float)(M_PI / 180.0);
    float Sx = rw / 7.0f;
    float Sy = rh / 7.0f;
    double th = (double)theta;
    float ca = (float)cos(th);
    float sa = (float)sin(th);

    float M00 = ca * Sx;
    float M01 = sa * Sy;
    float M02 = (M00 * (-3.5f) + M01 * (-3.5f)) + cx;
    float M10 = (-sa) * Sx;
    float M11 = ca * Sy;
    float M12 = (M10 * (-3.5f) + M11 * (-3.5f)) + cy;

    float pwf = (float)(bin % 7);
    float phf = (float)(bin / 7);
    float x0 = pwf, x1 = pwf + 1.0f;
    float y0 = phf, y1 = phf + 1.0f;

    float X00 = (M00 * x0 + M01 * y0) + M02;
    float X01 = (M00 * x0 + M01 * y1) + M02;
    float X10 = (M00 * x1 + M01 * y0) + M02;
    float X11 = (M00 * x1 + M01 * y1) + M02;
    float Y00 = (M10 * x0 + M11 * y0) + M12;
    float Y01 = (M10 * x0 + M11 * y1) + M12;
    float Y10 = (M10 * x1 + M11 * y0) + M12;
    float Y11 = (M10 * x1 + M11 * y1) + M12;

    float minX = fminf(fminf(X00, X01), fminf(X10, X11));
    float maxX = fmaxf(fmaxf(X00, X01), fmaxf(X10, X11));
    float minY = fminf(fminf(Y00, Y01), fminf(Y10, Y11));
    float maxY = fmaxf(fmaxf(Y00, Y01), fmaxf(Y10, Y11));

    float leftMost   = fmaxf(floorf(minX + 0.5f), 0.0f);
    float rightMost  = fminf(floorf(maxX + 0.5f), (float)(W_ - 1));
    float topMost    = fmaxf(floorf(minY + 0.5f), 0.0f);
    float bottomMost = fminf(floorf(maxY + 0.5f), (float)(H_ - 1));

    float bcx = (leftMost + rightMost) * 0.5f;
    float bcy = (topMost + bottomMost) * 0.5f;
    float fl = floorf(bcx), fr = ceilf(bcx);
    float ft = floorf(bcy), fb = ceilf(bcy);
    float rx = bcx - fl;
    float ry = bcy - ft;

    float wlt = (1.0f - rx) * (1.0f - ry);
    float wrt = rx * (1.0f - ry);
    float wrb = rx * ry;
    float wlb = (1.0f - rx) * ry;

    w[0] = wlt * edge_mask(ft, fl);
    w[1] = wrt * edge_mask(ft, fr);
    w[2] = wlb * edge_mask(fb, fl);
    w[3] = wrb * edge_mask(fb, fr);

    yt = min(max((int)ft, 0), H_ - 1);
    yb = min(max((int)fb, 0), H_ - 1);
    xl = min(max((int)fl, 0), W_ - 1);
    xr = min(max((int)fr, 0), W_ - 1);
}

// ---------------------------------------------------------------------------
// R9-proven transpose tile body (64x64, f32 LDS [64][65]) — byte-identical
// ---------------------------------------------------------------------------
__device__ __forceinline__ void transpose_tile(const float* __restrict__ in,
                                               unsigned short* __restrict__ xt,
                                               int b, int p0, int c0, int t,
                                               float (*tile)[65]) {
    const float*    ib = in + (size_t)b * C_ * HW_;
    unsigned short* ob = xt + (size_t)b * HW_ * C_;
    {
        int col4 = t & 15;             // which float4 along pixels
        int row  = t >> 4;             // channel row 0..15
        #pragma unroll
        for (int k = 0; k < 4; k++) {
            int c = row + k * 16;
            float4 v = *(const float4*)(ib + (size_t)(c0 + c) * HW_ + p0 + col4 * 4);
            int p = col4 * 4;
            tile[p + 0][c] = v.x;
            tile[p + 1][c] = v.y;
            tile[p + 2][c] = v.z;
            tile[p + 3][c] = v.w;
        }
    }
    __syncthreads();
    {
        int c8 = t & 7;                // which 8-channel group (16 B bf16)
        int pr = t >> 3;               // pixel row 0..31
        #pragma unroll
        for (int k = 0; k < 2; k++) {
            int p = pr + k * 32;
            ushort4 lo, hi;
            const float* tp = &tile[p][c8 * 8];
            lo.x = f2bf(tp[0]); lo.y = f2bf(tp[1]); lo.z = f2bf(tp[2]); lo.w = f2bf(tp[3]);
            hi.x = f2bf(tp[4]); hi.y = f2bf(tp[5]); hi.z = f2bf(tp[6]); hi.w = f2bf(tp[7]);
            unsigned short* dst = ob + (size_t)(p0 + p) * C_ + c0 + c8 * 8;
            *(ushort4*)(dst)     = lo;
            *(ushort4*)(dst + 4) = hi;
        }
    }
}

// ---------------------------------------------------------------------------
// R9-proven main body (bf16 lout, 2-bin unroll, nt copy-out) — byte-identical
// ---------------------------------------------------------------------------
__device__ __forceinline__ void bilerp4(uint2 lt, uint2 rt, uint2 lb, uint2 rb,
                                        float w0, float w1, float w2, float w3,
                                        float acc[4]) {
#pragma clang fp contract(off)
    float a0 = bf2f(lt.x & 0xFFFFu), a1 = bf2f(lt.x >> 16),
          a2 = bf2f(lt.y & 0xFFFFu), a3 = bf2f(lt.y >> 16);
    float b0 = bf2f(rt.x & 0xFFFFu), b1 = bf2f(rt.x >> 16),
          b2 = bf2f(rt.y & 0xFFFFu), b3 = bf2f(rt.y >> 16);
    float c0v = bf2f(lb.x & 0xFFFFu), c1v = bf2f(lb.x >> 16),
          c2v = bf2f(lb.y & 0xFFFFu), c3v = bf2f(lb.y >> 16);
    float d0 = bf2f(rb.x & 0xFFFFu), d1 = bf2f(rb.x >> 16),
          d2 = bf2f(rb.y & 0xFFFFu), d3 = bf2f(rb.y >> 16);
    acc[0] = ((w0 * a0 + w1 * b0) + w3 * d0) + w2 * c0v;
    acc[1] = ((w0 * a1 + w1 * b1) + w3 * d1) + w2 * c1v;
    acc[2] = ((w0 * a2 + w1 * b2) + w3 * d2) + w2 * c2v;
    acc[3] = ((w0 * a3 + w1 * b3) + w3 * d3) + w2 * c3v;
}

__device__ __forceinline__ void main_roi(const unsigned short* __restrict__ xt,
                                         const unsigned int* __restrict__ geom,
                                         float* __restrict__ outp, int r, int tid,
                                         unsigned short* lout) {
    int lane = tid & 63;
    int wv   = tid >> 6;
    int c4   = lane * 4;

    const uint4* gb = (const uint4*)(geom + (size_t)r * NBIN * 8);

    for (int b0 = wv; b0 < NBIN; b0 += 8) {
        int b1 = b0 + 4;
        uint4 go0 = gb[2 * b0];
        uint4 gu0 = gb[2 * b0 + 1];
        if (b1 < NBIN) {                        // wave-uniform; false only once
            uint4 go1 = gb[2 * b1];
            uint4 gu1 = gb[2 * b1 + 1];
            uint2 lt0 = *(const uint2*)(xt + go0.x + c4);
            uint2 rt0 = *(const uint2*)(xt + go0.y + c4);
            uint2 lb0 = *(const uint2*)(xt + go0.z + c4);
            uint2 rb0 = *(const uint2*)(xt + go0.w + c4);
            uint2 lt1 = *(const uint2*)(xt + go1.x + c4);
            uint2 rt1 = *(const uint2*)(xt + go1.y + c4);
            uint2 lb1 = *(const uint2*)(xt + go1.z + c4);
            uint2 rb1 = *(const uint2*)(xt + go1.w + c4);
            float acc0[4], acc1[4];
            bilerp4(lt0, rt0, lb0, rb0,
                    __uint_as_float(gu0.x), __uint_as_float(gu0.y),
                    __uint_as_float(gu0.z), __uint_as_float(gu0.w), acc0);
            bilerp4(lt1, rt1, lb1, rb1,
                    __uint_as_float(gu1.x), __uint_as_float(gu1.y),
                    __uint_as_float(gu1.z), __uint_as_float(gu1.w), acc1);
            #pragma unroll
            for (int jj = 0; jj < 4; jj++) {
                int j = (jj + (lane >> 3)) & 3;   // store-order swizzle
                float v0 = (j == 0) ? acc0[0] : (j == 1) ? acc0[1] : (j == 2) ? acc0[2] : acc0[3];
                float v1 = (j == 0) ? acc1[0] : (j == 1) ? acc1[1] : (j == 2) ? acc1[2] : acc1[3];
                lout[(c4 + j) * NBIN + b0] = f2bf(v0);
                lout[(c4 + j) * NBIN + b1] = f2bf(v1);
            }
        } else {
            uint2 lt0 = *(const uint2*)(xt + go0.x + c4);
            uint2 rt0 = *(const uint2*)(xt + go0.y + c4);
            uint2 lb0 = *(const uint2*)(xt + go0.z + c4);
            uint2 rb0 = *(const uint2*)(xt + go0.w + c4);
            float acc0[4];
            bilerp4(lt0, rt0, lb0, rb0,
                    __uint_as_float(gu0.x), __uint_as_float(gu0.y),
                    __uint_as_float(gu0.z), __uint_as_float(gu0.w), acc0);
            #pragma unroll
            for (int jj = 0; jj < 4; jj++) {
                int j = (jj + (lane >> 3)) & 3;
                float v0 = (j == 0) ? acc0[0] : (j == 1) ? acc0[1] : (j == 2) ? acc0[2] : acc0[3];
                lout[(c4 + j) * NBIN + b0] = f2bf(v0);
            }
        }
    }
    __syncthreads();

    const unsigned int* lu = (const unsigned int*)lout;
    float* obase = outp + (size_t)r * (C_ * NBIN);
    const int n4 = (C_ * NBIN) / 4;              // 3136
    for (int f = tid; f < n4; f += 256) {
        uint2 u = *(const uint2*)(&lu[2 * f]);   // 4 bf16
        v4f v;
        v.x = bf2f(u.x & 0xFFFFu); v.y = bf2f(u.x >> 16);
        v.z = bf2f(u.y & 0xFFFFu); v.w = bf2f(u.y >> 16);
        __builtin_nontemporal_store(v, (v4f*)(obase + 4 * f));
    }
}

#define SM_BYTES 25088   // max(64*65*4=16640 transpose, 256*49*2=25088 main)

// ---------------------------------------------------------------------------
// K1: transpose batch 0 (blocks 0..3399) + geometry table (blocks 3400..5099)
// ---------------------------------------------------------------------------
__global__ __launch_bounds__(256) void k1_t0_geom(const float* __restrict__ in,
                                                  unsigned short* __restrict__ xt,
                                                  unsigned int* __restrict__ geom,
                                                  const float* __restrict__ rois,
                                                  int R) {
    __shared__ __align__(16) char sm[SM_BYTES];
    int id = blockIdx.x;
    if (id < 3400) {
        transpose_tile(in, xt, 0, (id % 850) * 64, (id / 850) * 64,
                       threadIdx.x, (float(*)[65])sm);
        return;
    }
    int total = R * NBIN;
    for (int gid = (id - 3400) * 256 + threadIdx.x; gid < total; gid += 1700 * 256) {
        int r = gid / NBIN, bin = gid - r * NBIN;
        int b, yt, yb, xl, xr; float w[4];
        compute_geom(rois, r, bin, b, yt, yb, xl, xr, w);
        int base = b * HW_ * C_;
        uint4 o, wu;
        o.x = base + (yt * W_ + xl) * C_;
        o.y = base + (yt * W_ + xr) * C_;
        o.z = base + (yb * W_ + xl) * C_;
        o.w = base + (yb * W_ + xr) * C_;
        wu.x = __float_as_uint(w[0]);
        wu.y = __float_as_uint(w[1]);
        wu.z = __float_as_uint(w[2]);
        wu.w = __float_as_uint(w[3]);
        uint4* gp = (uint4*)(geom + (size_t)gid * 8);
        gp[0] = o;
        gp[1] = wu;
    }
}

// ---------------------------------------------------------------------------
// K2: transpose batch 1 (blocks 0..3399, dispatched first) OVERLAPPED with
// main for batch-0 rois (blocks 3400..3400+R-1; batch-1 rois exit early).
// Batch test: geom o.x = b*HW*C + pixoff*C < HW*C iff b==0.
// ---------------------------------------------------------------------------
__global__ __launch_bounds__(256) void k2_t1_main0(const float* __restrict__ in,
                                                   unsigned short* __restrict__ xt,
                                                   const unsigned int* __restrict__ geom,
                                                   float* __restrict__ outp,
                                                   int R) {
    __shared__ __align__(16) char sm[SM_BYTES];
    int id = blockIdx.x;
    if (id < 3400) {
        transpose_tile(in, xt, 1, (id % 850) * 64, (id / 850) * 64,
                       threadIdx.x, (float(*)[65])sm);
        return;
    }
    int r = id - 3400;
    if (r >= R) return;
    if (geom[(size_t)r * NBIN * 8] >= (unsigned int)(HW_ * C_)) return;  // batch 1
    main_roi(xt, geom, outp, r, threadIdx.x, (unsigned short*)sm);
}

// ---------------------------------------------------------------------------
// K3: main for batch-1 rois (batch-0 rois exit early)
// ---------------------------------------------------------------------------
__global__ __launch_bounds__(256) void k3_main1(const unsigned short* __restrict__ xt,
                                                const unsigned int* __restrict__ geom,
                                                float* __restrict__ outp) {
    __shared__ __align__(16) char sm[SM_BYTES];
    int r = blockIdx.x;
    if (geom[(size_t)r * NBIN * 8] < (unsigned int)(HW_ * C_)) return;   // batch 0
    main_roi(xt, geom, outp, r, threadIdx.x, (unsigned short*)sm);
}

// ---------------------------------------------------------------------------
// Fallback (no workspace): direct NCHW gather, thread = channel (f32 exact)
// ---------------------------------------------------------------------------
__global__ __launch_bounds__(256) void rroi_main_direct(const float* __restrict__ x,
                                                        const float* __restrict__ rois,
                                                        float* __restrict__ outp) {
    __shared__ float loutf[C_ * NBIN];
    __shared__ int   goff[NBIN][4];
    __shared__ float gw[NBIN][4];

    int r = blockIdx.x;
    int tid = threadIdx.x;

    if (tid < NBIN) {
        int b, yt, yb, xl, xr; float w[4];
        compute_geom(rois, r, tid, b, yt, yb, xl, xr, w);
        int base = b * C_ * HW_;
        goff[tid][0] = base + yt * W_ + xl;
        goff[tid][1] = base + yt * W_ + xr;
        goff[tid][2] = base + yb * W_ + xl;
        goff[tid][3] = base + yb * W_ + xr;
        gw[tid][0] = w[0]; gw[tid][1] = w[1]; gw[tid][2] = w[2]; gw[tid][3] = w[3];
    }
    __syncthreads();

    int c = tid;
    int coff = c * HW_;
    for (int bin = 0; bin < NBIN; bin++) {
        float w0 = gw[bin][0], w1 = gw[bin][1], w2 = gw[bin][2], w3 = gw[bin][3];
        float lt = x[goff[bin][0] + coff];
        float rt = x[goff[bin][1] + coff];
        float lb = x[goff[bin][2] + coff];
        float rb = x[goff[bin][3] + coff];
        float v;
        {
#pragma clang fp contract(off)
            v = ((w0 * lt + w1 * rt) + w3 * rb) + w2 * lb;
        }
        loutf[c * NBIN + bin] = v;
    }
    __syncthreads();

    float* o = outp + (size_t)r * (C_ * NBIN);
    const int n4 = (C_ * NBIN) / 4;
    for (int i = tid; i < n4; i += 256)
        *(float4*)(o + i * 4) = *(const float4*)(&loutf[i * 4]);
}

// ---------------------------------------------------------------------------
extern "C" void kernel_launch(void* const* d_in, const int* in_sizes, int n_in,
                              void* d_out, int out_size, void* d_ws, size_t ws_size,
                              hipStream_t stream) {
    const float* x    = (const float*)d_in[0];
    const float* rois = (const float*)d_in[1];
    float*       outp = (float*)d_out;
    int R = in_sizes[1] / 6;

    size_t geom_off = 64ull * 1024 * 1024;                       // after 55.7MB xt
    size_t need = geom_off + (size_t)R * NBIN * 8 * sizeof(unsigned int);
    if (ws_size >= need) {
        unsigned short* xt   = (unsigned short*)d_ws;
        unsigned int*   geom = (unsigned int*)((char*)d_ws + geom_off);
        k1_t0_geom<<<5100, 256, 0, stream>>>(x, xt, geom, rois, R);
        k2_t1_main0<<<3400 + R, 256, 0, stream>>>(x, xt, geom, outp, R);
        k3_main1<<<R, 256, 0, stream>>>(xt, geom, outp);
    } else {
        rroi_main_direct<<<R, 256, 0, stream>>>(x, rois, outp);
    }
}

// Round 11
// 60.747 us; speedup vs baseline: 1.1704x; 1.1704x over previous
//
#include <hip/hip_runtime.h>
#include <math.h>

#define B_   2
#define C_   256
#define H_   200
#define W_   272
#define HW_  (H_*W_)
#define NBIN 49
#define SCALE 0.0625f

typedef float v4f __attribute__((ext_vector_type(4)));

// ---------------------------------------------------------------------------
// bf16 helpers (staging only; all arithmetic stays f32)
// ---------------------------------------------------------------------------
__device__ __forceinline__ unsigned short f2bf(float f) {
    union { float f; unsigned int i; } v; v.f = f;
    unsigned int x = v.i;
    return (unsigned short)((x + 0x7FFFu + ((x >> 16) & 1u)) >> 16);   // RNE
}
__device__ __forceinline__ float bf2f(unsigned int u16) {
    union { unsigned int i; float f; } v; v.i = u16 << 16; return v.f;
}

// ---------------------------------------------------------------------------
// Geometry: bit-exact vs numpy f32 reference (verified: absmax 0.0 in R1).
// DO NOT TOUCH: fp contract off, same association order, f64 trig.
// ---------------------------------------------------------------------------
__device__ __forceinline__ float edge_mask(float yy, float xx) {
    return (yy > -1.0f && yy < (float)H_ && xx > -1.0f && xx < (float)W_) ? 1.0f : 0.0f;
}

__device__ void compute_geom(const float* __restrict__ rois, int r, int bin,
                             int& b, int& yt, int& yb, int& xl, int& xr,
                             float w[4]) {
#pragma clang fp contract(off)
    const float* rp = rois + r * 6;
    b = (int)rp[0];
    float cx = rp[1] * SCALE;
    float cy = rp[2] * SCALE;
    float rw = rp[3] * SCALE;
    float rh = rp[4] * SCALE;
    float theta = rp[5] * (float)(M_PI / 180.0);
    float Sx = rw / 7.0f;
    float Sy = rh / 7.0f;
    double th = (double)theta;
    float ca = (float)cos(th);
    float sa = (float)sin(th);

    float M00 = ca * Sx;
    float M01 = sa * Sy;
    float M02 = (M00 * (-3.5f) + M01 * (-3.5f)) + cx;
    float M10 = (-sa) * Sx;
    float M11 = ca * Sy;
    float M12 = (M10 * (-3.5f) + M11 * (-3.5f)) + cy;

    float pwf = (float)(bin % 7);
    float phf = (float)(bin / 7);
    float x0 = pwf, x1 = pwf + 1.0f;
    float y0 = phf, y1 = phf + 1.0f;

    float X00 = (M00 * x0 + M01 * y0) + M02;
    float X01 = (M00 * x0 + M01 * y1) + M02;
    float X10 = (M00 * x1 + M01 * y0) + M02;
    float X11 = (M00 * x1 + M01 * y1) + M02;
    float Y00 = (M10 * x0 + M11 * y0) + M12;
    float Y01 = (M10 * x0 + M11 * y1) + M12;
    float Y10 = (M10 * x1 + M11 * y0) + M12;
    float Y11 = (M10 * x1 + M11 * y1) + M12;

    float minX = fminf(fminf(X00, X01), fminf(X10, X11));
    float maxX = fmaxf(fmaxf(X00, X01), fmaxf(X10, X11));
    float minY = fminf(fminf(Y00, Y01), fminf(Y10, Y11));
    float maxY = fmaxf(fmaxf(Y00, Y01), fmaxf(Y10, Y11));

    float leftMost   = fmaxf(floorf(minX + 0.5f), 0.0f);
    float rightMost  = fminf(floorf(maxX + 0.5f), (float)(W_ - 1));
    float topMost    = fmaxf(floorf(minY + 0.5f), 0.0f);
    float bottomMost = fminf(floorf(maxY + 0.5f), (float)(H_ - 1));

    float bcx = (leftMost + rightMost) * 0.5f;
    float bcy = (topMost + bottomMost) * 0.5f;
    float fl = floorf(bcx), fr = ceilf(bcx);
    float ft = floorf(bcy), fb = ceilf(bcy);
    float rx = bcx - fl;
    float ry = bcy - ft;

    float wlt = (1.0f - rx) * (1.0f - ry);
    float wrt = rx * (1.0f - ry);
    float wrb = rx * ry;
    float wlb = (1.0f - rx) * ry;

    w[0] = wlt * edge_mask(ft, fl);
    w[1] = wrt * edge_mask(ft, fr);
    w[2] = wlb * edge_mask(fb, fl);
    w[3] = wrb * edge_mask(fb, fr);

    yt = min(max((int)ft, 0), H_ - 1);
    yb = min(max((int)fb, 0), H_ - 1);
    xl = min(max((int)fl, 0), W_ - 1);
    xr = min(max((int)fr, 0), W_ - 1);
}

// ---------------------------------------------------------------------------
// Kernel 1: NCHW f32 -> NHWC bf16 transpose (R2-proven 64x64 tile) PLUS a
// 5th blockIdx.y slice that precomputes the per-bin geometry table in ws.
// Byte-identical to R9 (T measured at its HBM floor, ~24.9 us).
// ---------------------------------------------------------------------------
__global__ __launch_bounds__(256) void transpose_geom(const float* __restrict__ in,
                                                      unsigned short* __restrict__ xt,
                                                      unsigned int* __restrict__ geom,
                                                      const float* __restrict__ rois,
                                                      int R) {
    if (blockIdx.y == 4) {
        int total = R * NBIN;
        for (int gid = (blockIdx.z * 850 + blockIdx.x) * 256 + threadIdx.x;
             gid < total; gid += 1700 * 256) {
            int r = gid / NBIN, bin = gid - r * NBIN;
            int b, yt, yb, xl, xr; float w[4];
            compute_geom(rois, r, bin, b, yt, yb, xl, xr, w);
            int base = b * HW_ * C_;
            uint4 o, wu;
            o.x = base + (yt * W_ + xl) * C_;
            o.y = base + (yt * W_ + xr) * C_;
            o.z = base + (yb * W_ + xl) * C_;
            o.w = base + (yb * W_ + xr) * C_;
            wu.x = __float_as_uint(w[0]);
            wu.y = __float_as_uint(w[1]);
            wu.z = __float_as_uint(w[2]);
            wu.w = __float_as_uint(w[3]);
            uint4* gp = (uint4*)(geom + (size_t)gid * 8);
            gp[0] = o;
            gp[1] = wu;
        }
        return;
    }

    __shared__ float tile[64][65];     // 16.6 KB
    int b  = blockIdx.z;
    int p0 = blockIdx.x * 64;          // spatial base
    int c0 = blockIdx.y * 64;          // channel base
    const float*    ib = in + (size_t)b * C_ * HW_;
    unsigned short* ob = xt + (size_t)b * HW_ * C_;
    int t = threadIdx.x;

    {
        int col4 = t & 15;             // which float4 along pixels
        int row  = t >> 4;             // channel row 0..15
        #pragma unroll
        for (int k = 0; k < 4; k++) {
            int c = row + k * 16;
            float4 v = *(const float4*)(ib + (size_t)(c0 + c) * HW_ + p0 + col4 * 4);
            int p = col4 * 4;
            tile[p + 0][c] = v.x;
            tile[p + 1][c] = v.y;
            tile[p + 2][c] = v.z;
            tile[p + 3][c] = v.w;
        }
    }
    __syncthreads();
    {
        int c8 = t & 7;                // which 8-channel group (16 B bf16)
        int pr = t >> 3;               // pixel row 0..31
        #pragma unroll
        for (int k = 0; k < 2; k++) {
            int p = pr + k * 32;
            ushort4 lo, hi;
            const float* tp = &tile[p][c8 * 8];
            lo.x = f2bf(tp[0]); lo.y = f2bf(tp[1]); lo.z = f2bf(tp[2]); lo.w = f2bf(tp[3]);
            hi.x = f2bf(tp[4]); hi.y = f2bf(tp[5]); hi.z = f2bf(tp[6]); hi.w = f2bf(tp[7]);
            unsigned short* dst = ob + (size_t)(p0 + p) * C_ + c0 + c8 * 8;
            *(ushort4*)(dst)     = lo;
            *(ushort4*)(dst + 4) = hi;
        }
    }
}

// ---------------------------------------------------------------------------
// Kernel 2: R9 structure + 3-bin unroll (12 independent tap loads in flight).
// Bins per wave: {wv + 4k}; iteration covers k=3i,3i+1,3i+2 (stride 12).
// Guards are wave-uniform; only the full-3 and single-bin paths execute.
// ---------------------------------------------------------------------------
__device__ __forceinline__ void bilerp4(uint2 lt, uint2 rt, uint2 lb, uint2 rb,
                                        float w0, float w1, float w2, float w3,
                                        float acc[4]) {
#pragma clang fp contract(off)
    float a0 = bf2f(lt.x & 0xFFFFu), a1 = bf2f(lt.x >> 16),
          a2 = bf2f(lt.y & 0xFFFFu), a3 = bf2f(lt.y >> 16);
    float b0 = bf2f(rt.x & 0xFFFFu), b1 = bf2f(rt.x >> 16),
          b2 = bf2f(rt.y & 0xFFFFu), b3 = bf2f(rt.y >> 16);
    float c0v = bf2f(lb.x & 0xFFFFu), c1v = bf2f(lb.x >> 16),
          c2v = bf2f(lb.y & 0xFFFFu), c3v = bf2f(lb.y >> 16);
    float d0 = bf2f(rb.x & 0xFFFFu), d1 = bf2f(rb.x >> 16),
          d2 = bf2f(rb.y & 0xFFFFu), d3 = bf2f(rb.y >> 16);
    acc[0] = ((w0 * a0 + w1 * b0) + w3 * d0) + w2 * c0v;
    acc[1] = ((w0 * a1 + w1 * b1) + w3 * d1) + w2 * c1v;
    acc[2] = ((w0 * a2 + w1 * b2) + w3 * d2) + w2 * c2v;
    acc[3] = ((w0 * a3 + w1 * b3) + w3 * d3) + w2 * c3v;
}

__device__ __forceinline__ void store_bin(unsigned short* lout, int c4, int lane,
                                          int bin, const float acc[4]) {
    #pragma unroll
    for (int jj = 0; jj < 4; jj++) {
        int j = (jj + (lane >> 3)) & 3;        // store-order swizzle
        float v = (j == 0) ? acc[0] : (j == 1) ? acc[1] : (j == 2) ? acc[2] : acc[3];
        lout[(c4 + j) * NBIN + bin] = f2bf(v);
    }
}

__global__ __launch_bounds__(256) void rroi_main_bf16(const unsigned short* __restrict__ xt,
                                                      const unsigned int* __restrict__ geom,
                                                      float* __restrict__ outp) {
    __shared__ unsigned short lout[C_ * NBIN];   // 25088 B -> 6 blocks/CU

    int r    = blockIdx.x;
    int tid  = threadIdx.x;
    int lane = tid & 63;
    int wv   = tid >> 6;
    int c4   = lane * 4;

    const uint4* gb = (const uint4*)(geom + (size_t)r * NBIN * 8);

    for (int b0 = wv; b0 < NBIN; b0 += 12) {
        int b1 = b0 + 4, b2 = b0 + 8;
        uint4 go0 = gb[2 * b0];
        uint4 gu0 = gb[2 * b0 + 1];
        if (b2 < NBIN) {
            uint4 go1 = gb[2 * b1];
            uint4 gu1 = gb[2 * b1 + 1];
            uint4 go2 = gb[2 * b2];
            uint4 gu2 = gb[2 * b2 + 1];
            // 12 independent tap loads in flight
            uint2 lt0 = *(const uint2*)(xt + go0.x + c4);
            uint2 rt0 = *(const uint2*)(xt + go0.y + c4);
            uint2 lb0 = *(const uint2*)(xt + go0.z + c4);
            uint2 rb0 = *(const uint2*)(xt + go0.w + c4);
            uint2 lt1 = *(const uint2*)(xt + go1.x + c4);
            uint2 rt1 = *(const uint2*)(xt + go1.y + c4);
            uint2 lb1 = *(const uint2*)(xt + go1.z + c4);
            uint2 rb1 = *(const uint2*)(xt + go1.w + c4);
            uint2 lt2 = *(const uint2*)(xt + go2.x + c4);
            uint2 rt2 = *(const uint2*)(xt + go2.y + c4);
            uint2 lb2 = *(const uint2*)(xt + go2.z + c4);
            uint2 rb2 = *(const uint2*)(xt + go2.w + c4);
            float acc0[4], acc1[4], acc2[4];
            bilerp4(lt0, rt0, lb0, rb0,
                    __uint_as_float(gu0.x), __uint_as_float(gu0.y),
                    __uint_as_float(gu0.z), __uint_as_float(gu0.w), acc0);
            bilerp4(lt1, rt1, lb1, rb1,
                    __uint_as_float(gu1.x), __uint_as_float(gu1.y),
                    __uint_as_float(gu1.z), __uint_as_float(gu1.w), acc1);
            bilerp4(lt2, rt2, lb2, rb2,
                    __uint_as_float(gu2.x), __uint_as_float(gu2.y),
                    __uint_as_float(gu2.z), __uint_as_float(gu2.w), acc2);
            store_bin(lout, c4, lane, b0, acc0);
            store_bin(lout, c4, lane, b1, acc1);
            store_bin(lout, c4, lane, b2, acc2);
        } else if (b1 < NBIN) {
            uint4 go1 = gb[2 * b1];
            uint4 gu1 = gb[2 * b1 + 1];
            uint2 lt0 = *(const uint2*)(xt + go0.x + c4);
            uint2 rt0 = *(const uint2*)(xt + go0.y + c4);
            uint2 lb0 = *(const uint2*)(xt + go0.z + c4);
            uint2 rb0 = *(const uint2*)(xt + go0.w + c4);
            uint2 lt1 = *(const uint2*)(xt + go1.x + c4);
            uint2 rt1 = *(const uint2*)(xt + go1.y + c4);
            uint2 lb1 = *(const uint2*)(xt + go1.z + c4);
            uint2 rb1 = *(const uint2*)(xt + go1.w + c4);
            float acc0[4], acc1[4];
            bilerp4(lt0, rt0, lb0, rb0,
                    __uint_as_float(gu0.x), __uint_as_float(gu0.y),
                    __uint_as_float(gu0.z), __uint_as_float(gu0.w), acc0);
            bilerp4(lt1, rt1, lb1, rb1,
                    __uint_as_float(gu1.x), __uint_as_float(gu1.y),
                    __uint_as_float(gu1.z), __uint_as_float(gu1.w), acc1);
            store_bin(lout, c4, lane, b0, acc0);
            store_bin(lout, c4, lane, b1, acc1);
        } else {
            uint2 lt0 = *(const uint2*)(xt + go0.x + c4);
            uint2 rt0 = *(const uint2*)(xt + go0.y + c4);
            uint2 lb0 = *(const uint2*)(xt + go0.z + c4);
            uint2 rb0 = *(const uint2*)(xt + go0.w + c4);
            float acc0[4];
            bilerp4(lt0, rt0, lb0, rb0,
                    __uint_as_float(gu0.x), __uint_as_float(gu0.y),
                    __uint_as_float(gu0.z), __uint_as_float(gu0.w), acc0);
            store_bin(lout, c4, lane, b0, acc0);
        }
    }
    __syncthreads();

    // Copy-out: lane f -> output float4 f (16 B contiguous per lane)
    const unsigned int* lu = (const unsigned int*)lout;
    float* obase = outp + (size_t)r * (C_ * NBIN);
    const int n4 = (C_ * NBIN) / 4;              // 3136
    for (int f = tid; f < n4; f += 256) {
        uint2 u = *(const uint2*)(&lu[2 * f]);   // 4 bf16
        v4f v;
        v.x = bf2f(u.x & 0xFFFFu); v.y = bf2f(u.x >> 16);
        v.z = bf2f(u.y & 0xFFFFu); v.w = bf2f(u.y >> 16);
        __builtin_nontemporal_store(v, (v4f*)(obase + 4 * f));
    }
}

// ---------------------------------------------------------------------------
// Fallback (no workspace): direct NCHW gather, thread = channel (f32 exact)
// ---------------------------------------------------------------------------
__global__ __launch_bounds__(256) void rroi_main_direct(const float* __restrict__ x,
                                                        const float* __restrict__ rois,
                                                        float* __restrict__ outp) {
    __shared__ float loutf[C_ * NBIN];
    __shared__ int   goff[NBIN][4];
    __shared__ float gw[NBIN][4];

    int r = blockIdx.x;
    int tid = threadIdx.x;

    if (tid < NBIN) {
        int b, yt, yb, xl, xr; float w[4];
        compute_geom(rois, r, tid, b, yt, yb, xl, xr, w);
        int base = b * C_ * HW_;
        goff[tid][0] = base + yt * W_ + xl;
        goff[tid][1] = base + yt * W_ + xr;
        goff[tid][2] = base + yb * W_ + xl;
        goff[tid][3] = base + yb * W_ + xr;
        gw[tid][0] = w[0]; gw[tid][1] = w[1]; gw[tid][2] = w[2]; gw[tid][3] = w[3];
    }
    __syncthreads();

    int c = tid;
    int coff = c * HW_;
    for (int bin = 0; bin < NBIN; bin++) {
        float w0 = gw[bin][0], w1 = gw[bin][1], w2 = gw[bin][2], w3 = gw[bin][3];
        float lt = x[goff[bin][0] + coff];
        float rt = x[goff[bin][1] + coff];
        float lb = x[goff[bin][2] + coff];
        float rb = x[goff[bin][3] + coff];
        float v;
        {
#pragma clang fp contract(off)
            v = ((w0 * lt + w1 * rt) + w3 * rb) + w2 * lb;
        }
        loutf[c * NBIN + bin] = v;
    }
    __syncthreads();

    float* o = outp + (size_t)r * (C_ * NBIN);
    const int n4 = (C_ * NBIN) / 4;
    for (int i = tid; i < n4; i += 256)
        *(float4*)(o + i * 4) = *(const float4*)(&loutf[i * 4]);
}

// ---------------------------------------------------------------------------
extern "C" void kernel_launch(void* const* d_in, const int* in_sizes, int n_in,
                              void* d_out, int out_size, void* d_ws, size_t ws_size,
                              hipStream_t stream) {
    const float* x    = (const float*)d_in[0];
    const float* rois = (const float*)d_in[1];
    float*       outp = (float*)d_out;
    int R = in_sizes[1] / 6;

    size_t geom_off = 64ull * 1024 * 1024;                       // after 55.7MB xt
    size_t need = geom_off + (size_t)R * NBIN * 8 * sizeof(unsigned int);
    if (ws_size >= need) {
        unsigned short* xt   = (unsigned short*)d_ws;
        unsigned int*   geom = (unsigned int*)((char*)d_ws + geom_off);
        dim3 g(HW_ / 64, 5, B_);       // y<4: transpose tiles; y==4: geometry
        transpose_geom<<<g, 256, 0, stream>>>(x, xt, geom, rois, R);
        rroi_main_bf16<<<R, 256, 0, stream>>>(xt, geom, outp);
    } else {
        rroi_main_direct<<<R, 256, 0, stream>>>(x, rois, outp);
    }
}